// Round 1
// baseline (102.560 us; speedup 1.0000x reference)
//
#include <hip/hip_runtime.h>

// Problem constants (match reference)
#define NPTS   128
#define NSTEPS 64
#define NEV    4096
#define NPAIR  4000
#define DELTA_F (100.0f / 63.0f)
#define EPSF    1e-9f
#define SQRTPI_OVER2 0.88622692545275801365f  // sqrt(pi)/2

// Workspace layout (d_ws):
//   [0]  double accum[2]   : accum[0] = sum of d_pairs over (p,e); accum[1] = non-event sum
//   [16] float  S1[64]     : per-step sum of a_e
//   [16+256] float S2[64]  : per-step sum of a_e^2
#define WS_ACCUM_OFF 0
#define WS_S1_OFF    16
#define WS_S2_OFF    (16 + 64 * 4)
#define WS_TOTAL_BYTES (16 + 64 * 4 * 2)

__device__ __forceinline__ void block_reduce_atomic(float v, double* target) {
    // wave (64-lane) shuffle reduce
    #pragma unroll
    for (int off = 32; off > 0; off >>= 1) v += __shfl_down(v, off, 64);
    __shared__ float ws[4];
    int lane = threadIdx.x & 63;
    int wid  = threadIdx.x >> 6;
    if (lane == 0) ws[wid] = v;
    __syncthreads();
    if (threadIdx.x == 0) {
        float tot = ws[0] + ws[1] + ws[2] + ws[3];
        atomicAdd(target, (double)tot);
    }
}

// Bucket events by time-step: S1[s] = sum a_e, S2[s] = sum a_e^2,
// where a_e = td[s_e] + frac_e  (td[0]=0, td[s>0]=DELTA)
__global__ void stats_kernel(const float* __restrict__ event_times,
                             float* __restrict__ S1, float* __restrict__ S2) {
    __shared__ float s1[NSTEPS], s2[NSTEPS];
    int t = threadIdx.x;
    if (t < NSTEPS) { s1[t] = 0.f; s2[t] = 0.f; }
    __syncthreads();
    for (int e = t; e < NEV; e += blockDim.x) {
        float tv = event_times[e] / DELTA_F;
        float tf = floorf(tv);
        float f  = tv - tf;
        int s = (int)tf;
        s = s < 0 ? 0 : (s > NSTEPS - 1 ? NSTEPS - 1 : s);
        float a = (s == 0 ? 0.f : DELTA_F) + f;
        atomicAdd(&s1[s], a);
        atomicAdd(&s2[s], a * a);
    }
    __syncthreads();
    if (t < NSTEPS) { S1[t] = s1[t]; S2[t] = s2[t]; }
}

// Event term: accumulate sum over (p, e) of d_pairs via per-step factorization.
// item index = p*64 + s  (lane-contiguous in s -> coalesced v0 reads)
__global__ void event_kernel(const float* __restrict__ z0,
                             const float* __restrict__ v0,
                             const int*   __restrict__ pi,
                             const int*   __restrict__ pj,
                             const float* __restrict__ S1,
                             const float* __restrict__ S2,
                             double* __restrict__ accum) {
    const int total = NPAIR * NSTEPS;
    float local = 0.f;
    for (int idx = blockIdx.x * blockDim.x + threadIdx.x; idx < total;
         idx += gridDim.x * blockDim.x) {
        int s = idx & (NSTEPS - 1);
        int p = idx >> 6;
        int i = pi[p], j = pj[p];
        float dz0x = z0[i * 2 + 0] - z0[j * 2 + 0];
        float dz0y = z0[i * 2 + 1] - z0[j * 2 + 1];
        float dvx = v0[(i * 2 + 0) * NSTEPS + s] - v0[(j * 2 + 0) * NSTEPS + s];
        float dvy = v0[(i * 2 + 1) * NSTEPS + s] - v0[(j * 2 + 1) * NSTEPS + s];
        float Q1 = dz0x * dvx + dz0y * dvy;
        float Q2 = dvx * dvx + dvy * dvy;
        float term = 2.f * S1[s] * Q1 + S2[s] * Q2;
        if (s == 0) {
            // E * Q0[p], added once per pair
            term += (float)NEV * (dz0x * dz0x + dz0y * dz0y);
        }
        local += term;
    }
    block_reduce_atomic(local, accum + 0);
}

// Non-event term: sum over i<j, s of analytic integral.
// item index = ((i*N + j) * 64) + s : one wave handles one (i,j) across all s,
// so the j>i predicate is wave-uniform and v0 loads are stride-1 in s.
__global__ void nonevent_kernel(const float* __restrict__ beta,
                                const float* __restrict__ z0,
                                const float* __restrict__ v0,
                                double* __restrict__ accum) {
    const float b = beta[0];
    const int total = NPTS * NPTS * NSTEPS;
    float local = 0.f;
    for (int idx = blockIdx.x * blockDim.x + threadIdx.x; idx < total;
         idx += gridDim.x * blockDim.x) {
        int s  = idx & (NSTEPS - 1);
        int ij = idx >> 6;
        int i  = ij >> 7;          // / NPTS
        int j  = ij & (NPTS - 1);  // % NPTS
        if (j > i) {
            float td = (s == 0) ? 0.f : DELTA_F;
            float vix = v0[(i * 2 + 0) * NSTEPS + s];
            float viy = v0[(i * 2 + 1) * NSTEPS + s];
            float vjx = v0[(j * 2 + 0) * NSTEPS + s];
            float vjy = v0[(j * 2 + 1) * NSTEPS + s];
            float dvx = vix - vjx;
            float dvy = viy - vjy;
            // dz = (z0_i - z0_j) + (v_i - v_j) * td[s]
            float dzx = (z0[i * 2 + 0] - z0[j * 2 + 0]) + dvx * td;
            float dzy = (z0[i * 2 + 1] - z0[j * 2 + 1]) + dvy * td;
            float r2  = dvx * dvx + dvy * dvy + EPSF;
            float r   = sqrtf(r2);
            float zdv = dzx * dvx + dzy * dvy;
            float bsh = zdv / r2;
            float cc  = dzx * dzx + dzy * dzy - zdv * zdv / r2;
            float integ = expf(b - cc) * (SQRTPI_OVER2 / r) *
                          (erff(r * (td + bsh)) - erff(r * bsh));
            local += integ;
        }
    }
    block_reduce_atomic(local, accum + 1);
}

__global__ void finalize_kernel(const float* __restrict__ beta,
                                const double* __restrict__ accum,
                                float* __restrict__ out) {
    double ev = (double)beta[0] * (double)NPAIR * (double)NEV - accum[0];
    out[0] = (float)(ev - accum[1]);
}

extern "C" void kernel_launch(void* const* d_in, const int* in_sizes, int n_in,
                              void* d_out, int out_size, void* d_ws, size_t ws_size,
                              hipStream_t stream) {
    const float* beta        = (const float*)d_in[0];
    const float* z0          = (const float*)d_in[1];
    const float* v0          = (const float*)d_in[2];
    const float* event_times = (const float*)d_in[3];
    // d_in[4] = t0, d_in[5] = tn : unused (constants folded)
    const int* pairs_i = (const int*)d_in[6];
    const int* pairs_j = (const int*)d_in[7];
    float* out = (float*)d_out;

    char* ws = (char*)d_ws;
    double* accum = (double*)(ws + WS_ACCUM_OFF);
    float*  S1    = (float*)(ws + WS_S1_OFF);
    float*  S2    = (float*)(ws + WS_S2_OFF);

    hipMemsetAsync(d_ws, 0, WS_TOTAL_BYTES, stream);

    stats_kernel<<<1, 256, 0, stream>>>(event_times, S1, S2);
    event_kernel<<<512, 256, 0, stream>>>(z0, v0, pairs_i, pairs_j, S1, S2, accum);
    nonevent_kernel<<<1024, 256, 0, stream>>>(beta, z0, v0, accum);
    finalize_kernel<<<1, 1, 0, stream>>>(beta, accum, out);
}

// Round 2
// 88.541 us; speedup vs baseline: 1.1583x; 1.1583x over previous
//
#include <hip/hip_runtime.h>

// Problem constants (match reference)
#define NPTS   128
#define NSTEPS 64
#define NEV    4096
#define NPAIR  4000
#define DELTA_F (100.0f / 63.0f)
#define EPSF    1e-9f
#define SQRTPI_OVER2 0.88622692545275801365f  // sqrt(pi)/2

#define GRID 256
#define BLK  256

// d_ws layout: float partials[2*GRID]  (ev sums, then ne sums)
// Every block writes its slot unconditionally -> no init needed.

__global__ __launch_bounds__(BLK) void fused_kernel(
    const float* __restrict__ beta,
    const float* __restrict__ z0,
    const float* __restrict__ v0,
    const float* __restrict__ event_times,
    const int*   __restrict__ pi,
    const int*   __restrict__ pj,
    float* __restrict__ partials) {
    __shared__ float s1[NSTEPS], s2[NSTEPS];
    __shared__ float zsh[NPTS * 2];
    const int t = threadIdx.x;

    // --- Phase A: per-block redundant event stats (S1[s]=sum a, S2[s]=sum a^2) ---
    if (t < NSTEPS) { s1[t] = 0.f; s2[t] = 0.f; }
    zsh[t] = z0[t];                      // 256 threads == 256 floats of z0
    __syncthreads();
    for (int e = t; e < NEV; e += BLK) {
        float tv = event_times[e] / DELTA_F;
        float tf = floorf(tv);
        float f  = tv - tf;
        int s = (int)tf;
        s = s < 0 ? 0 : (s > NSTEPS - 1 ? NSTEPS - 1 : s);
        float a = (s == 0 ? 0.f : DELTA_F) + f;
        atomicAdd(&s1[s], a);
        atomicAdd(&s2[s], a * a);
    }
    __syncthreads();

    const float b = beta[0];

    // --- Phase B: event term, factorized per (pair, step) ---
    // sum_{p,e} d_pairs = E*sum_p Q0 + sum_{p,s} (2*S1[s]*Q1 + S2[s]*Q2)
    float lev = 0.f;
    for (int idx = blockIdx.x * BLK + t; idx < NPAIR * NSTEPS; idx += GRID * BLK) {
        int s = idx & (NSTEPS - 1);
        int p = idx >> 6;
        int i = pi[p], j = pj[p];
        float dz0x = zsh[i * 2 + 0] - zsh[j * 2 + 0];
        float dz0y = zsh[i * 2 + 1] - zsh[j * 2 + 1];
        float dvx = v0[(i * 2 + 0) * NSTEPS + s] - v0[(j * 2 + 0) * NSTEPS + s];
        float dvy = v0[(i * 2 + 1) * NSTEPS + s] - v0[(j * 2 + 1) * NSTEPS + s];
        float Q1 = dz0x * dvx + dz0y * dvy;
        float Q2 = dvx * dvx + dvy * dvy;
        float term = 2.f * s1[s] * Q1 + s2[s] * Q2;
        if (s == 0) term += (float)NEV * (dz0x * dz0x + dz0y * dz0y);
        lev += term;
    }

    // --- Phase C: non-event term (analytic integral), i<j, per step ---
    float lne = 0.f;
    for (int idx = blockIdx.x * BLK + t; idx < NPTS * NPTS * NSTEPS; idx += GRID * BLK) {
        int s  = idx & (NSTEPS - 1);
        int ij = idx >> 6;
        int i  = ij >> 7;          // / NPTS
        int j  = ij & (NPTS - 1);  // % NPTS
        if (j > i) {
            float td = (s == 0) ? 0.f : DELTA_F;
            float dvx = v0[(i * 2 + 0) * NSTEPS + s] - v0[(j * 2 + 0) * NSTEPS + s];
            float dvy = v0[(i * 2 + 1) * NSTEPS + s] - v0[(j * 2 + 1) * NSTEPS + s];
            float dzx = (zsh[i * 2 + 0] - zsh[j * 2 + 0]) + dvx * td;
            float dzy = (zsh[i * 2 + 1] - zsh[j * 2 + 1]) + dvy * td;
            float r2  = dvx * dvx + dvy * dvy + EPSF;
            float r   = sqrtf(r2);
            float zdv = dzx * dvx + dzy * dvy;
            float bsh = zdv / r2;
            float cc  = dzx * dzx + dzy * dzy - zdv * zdv / r2;
            lne += expf(b - cc) * (SQRTPI_OVER2 / r) *
                   (erff(r * (td + bsh)) - erff(r * bsh));
        }
    }

    // --- block reduce both accumulators, write partials (no atomics) ---
    #pragma unroll
    for (int off = 32; off > 0; off >>= 1) {
        lev += __shfl_down(lev, off, 64);
        lne += __shfl_down(lne, off, 64);
    }
    __shared__ float wsv[4], wsn[4];
    int lane = t & 63, wid = t >> 6;
    if (lane == 0) { wsv[wid] = lev; wsn[wid] = lne; }
    __syncthreads();
    if (t == 0) {
        partials[blockIdx.x]        = wsv[0] + wsv[1] + wsv[2] + wsv[3];
        partials[GRID + blockIdx.x] = wsn[0] + wsn[1] + wsn[2] + wsn[3];
    }
}

__global__ void finalize_kernel(const float* __restrict__ beta,
                                const float* __restrict__ partials,
                                float* __restrict__ out) {
    int lane = threadIdx.x;
    double ev = 0.0, ne = 0.0;
    for (int k = lane; k < GRID; k += 64) {
        ev += (double)partials[k];
        ne += (double)partials[GRID + k];
    }
    #pragma unroll
    for (int off = 32; off > 0; off >>= 1) {
        ev += __shfl_down(ev, off, 64);
        ne += __shfl_down(ne, off, 64);
    }
    if (lane == 0) {
        double evt = (double)beta[0] * (double)NPAIR * (double)NEV - ev;
        out[0] = (float)(evt - ne);
    }
}

extern "C" void kernel_launch(void* const* d_in, const int* in_sizes, int n_in,
                              void* d_out, int out_size, void* d_ws, size_t ws_size,
                              hipStream_t stream) {
    const float* beta        = (const float*)d_in[0];
    const float* z0          = (const float*)d_in[1];
    const float* v0          = (const float*)d_in[2];
    const float* event_times = (const float*)d_in[3];
    // d_in[4] = t0, d_in[5] = tn : unused (constants folded)
    const int* pairs_i = (const int*)d_in[6];
    const int* pairs_j = (const int*)d_in[7];
    float* out = (float*)d_out;
    float* partials = (float*)d_ws;

    fused_kernel<<<GRID, BLK, 0, stream>>>(beta, z0, v0, event_times,
                                           pairs_i, pairs_j, partials);
    finalize_kernel<<<1, 64, 0, stream>>>(beta, partials, out);
}